// Round 14
// baseline (107.230 us; speedup 1.0000x reference)
//
#include <hip/hip_runtime.h>
#include <hip/hip_bf16.h>
#include <cstdint>
#include <cstddef>

// SlideAttention fused pipeline for MI355X (gfx950).
// B=8, H=W=64, C=256, HEADS=8, U=32, WIN=3 (9 taps), CPB=512.
//
// R14 = best-measured pieces: k_attn back to R10 structure (256 thr,
// dkw2 strided weights, 61.0us measured) + all-81-tap conv (identity
// weights are exactly 1.0 in the input) + interior-block fast path.
// k_pre merge (setup+transpose) kept from R13.

typedef __attribute__((ext_vector_type(4))) float f32x4;
typedef __attribute__((ext_vector_type(8))) short s16x8;
typedef __attribute__((ext_vector_type(4))) int   i32x4;
typedef _Float16 h2 __attribute__((ext_vector_type(2)));

#define DEVINL __device__ __forceinline__

DEVINL unsigned short f2bf(float f) {  // RNE, finite inputs only
    unsigned int u = __builtin_bit_cast(unsigned int, f);
    u += 0x7FFFu + ((u >> 16) & 1u);
    return (unsigned short)(u >> 16);
}
// LDS xor-swizzle for GEMM tiles (rows 128 B)
DEVINL int swz(int off) { return off ^ ((off >> 3) & 0x70); }

DEVINL float fexp2(float x) {
#if __has_builtin(__builtin_amdgcn_exp2f)
    return __builtin_amdgcn_exp2f(x);
#else
    return exp2f(x);
#endif
}
DEVINL float fdot2f(h2 a, h2 b, float c) {
#if __has_builtin(__builtin_amdgcn_fdot2)
    return __builtin_amdgcn_fdot2(a, b, c, false);
#else
    return fmaf((float)a.x, (float)b.x, fmaf((float)a.y, (float)b.y, c));
#endif
}

// ------------------------------------------------------- pre (setup+tr) ----
// 576 threads. Block 0: CPB MLP rel_bias + exp(scale) (log2-domain).
// Blocks 1..: dk -> dkw2 (l*128+pr) pairs; w_qkv -> wT bf16; proj_w -> pT
// f16 (pair-permuted).
__global__ void k_pre(const float* __restrict__ scale,
                      const float* __restrict__ w1,
                      const float* __restrict__ b1,
                      const float* __restrict__ w2,
                      const float* __restrict__ dk,
                      const float* __restrict__ wq,
                      const float* __restrict__ pw,
                      float* __restrict__ relb,
                      float* __restrict__ escale,
                      unsigned int* __restrict__ dkw2,
                      unsigned short* __restrict__ wT,
                      unsigned short* __restrict__ pT) {
    const int t = threadIdx.x;
    if (blockIdx.x == 0) {
        __shared__ float hbuf[512 * 9];
        __shared__ float part[8][72];
        const float LOG2E = 1.4426950408889634f;
        if (t < 512) {
            float wa = w1[t], wb = w1[512 + t], bb = b1[t];
            #pragma unroll
            for (int m = 0; m < 9; ++m) {
                float dy = (float)(m / 3 - 1), dx = (float)(m % 3 - 1);
                const float il8 = 0.48089834696298783f; // 1/ln(8)
                float r0 = (dy > 0.f ? 1.f : (dy < 0.f ? -1.f : 0.f)) * log1pf(fabsf(dy)) * il8;
                float r1 = (dx > 0.f ? 1.f : (dx < 0.f ? -1.f : 0.f)) * log1pf(fabsf(dx)) * il8;
                hbuf[t * 9 + m] = fmaxf(r0 * wa + r1 * wb + bb, 0.f);
            }
        }
        __syncthreads();
        {
            int chunk = t / 72, mh = t % 72;
            int m = mh / 8, head = mh % 8;
            float acc = 0.f;
            #pragma unroll 8
            for (int j = chunk * 64; j < chunk * 64 + 64; ++j)
                acc = fmaf(hbuf[j * 9 + m], w2[j * 8 + head], acc);
            part[chunk][mh] = acc;
        }
        __syncthreads();
        if (t < 72) {
            int m = t / 8, head = t % 8;
            float acc = 0.f;
            #pragma unroll
            for (int ch = 0; ch < 8; ++ch) acc += part[ch][t];
            relb[head * 9 + m] = 16.f / (1.f + expf(-acc)) * LOG2E;
        } else if (t < 80) {
            escale[t - 72] = expf(scale[t - 72]) * LOG2E;
        }
        return;
    }
    int i = (blockIdx.x - 1) * 576 + t;
    if (i < 10368) {   // dkw2[l*128+pr] = (f16 dk[tap][c][m], f16 dk[tap][c+16][m])
        int l = i >> 7, pr = i & 127;
        int tap = l / 9, m = l % 9;
        int c = (pr >> 4) * 32 + (pr & 15);
        float f0 = dk[(tap * 256 + c) * 9 + m];
        float f1 = dk[(tap * 256 + c + 16) * 9 + m];
        unsigned short h0 = __builtin_bit_cast(unsigned short, (_Float16)f0);
        unsigned short h1 = __builtin_bit_cast(unsigned short, (_Float16)f1);
        dkw2[i] = (unsigned int)h0 | ((unsigned int)h1 << 16);
        return;
    }
    int j = i - 10368;
    if (j < 196608) {                   // wT[n*256+k] = bf16(wq[k*768+n])
        int n = j >> 8, k = j & 255;
        wT[j] = f2bf(wq[k * 768 + n]);
        return;
    }
    int p = j - 196608;
    if (p < 65536) {   // pT[n*256+kp] = f16(pw[c(kp)*256+n]), pair-permuted K
        int n = p >> 8, kp = p & 255;
        int head = kp >> 5, tt = kp & 31, ci = tt >> 1, jj = tt & 1;
        int c = head * 32 + ci + 16 * jj;
        pT[p] = __builtin_bit_cast(unsigned short, (_Float16)pw[c * 256 + n]);
    }
}

// ------------------------------------------------------------- qkv GEMM ----
// 768 blocks; XCD-chunked so the 3 N-tiles of one M-tile land on one XCD L2.
__launch_bounds__(512, 1)
__global__ void k_qkv_gemm(const float* __restrict__ x,
                           const unsigned short* __restrict__ wT,
                           const float* __restrict__ qb,
                           const float* __restrict__ vb,
                           unsigned short* __restrict__ qkv) {
    __shared__ __align__(16) unsigned short As[128 * 64];
    __shared__ __align__(16) unsigned short Bs[256 * 64];
    const int orig = blockIdx.x;
    const int tile = (orig & 7) * 96 + (orig >> 3);   // 768 = 8 XCD x 96
    const int m0 = (tile / 3) * 128;
    const int n0 = (tile % 3) * 256;
    const int t = threadIdx.x;
    const int wid = t >> 6, lane = t & 63;
    const int wm = wid >> 2, wn = wid & 3;
    const int lr = lane & 15, lk = lane >> 4;
    const int ar = t >> 2, aq = t & 3;
    const int bn = t >> 1, bh = t & 1;
    f32x4 acc[4][4] = {};

    for (int ks = 0; ks < 256; ks += 64) {
        {   // stage A (f32 -> bf16)
            const float* src = x + (size_t)(m0 + ar) * 256 + ks + aq * 16;
            f32x4 v0 = *(const f32x4*)(src + 0);
            f32x4 v1 = *(const f32x4*)(src + 4);
            f32x4 v2 = *(const f32x4*)(src + 8);
            f32x4 v3 = *(const f32x4*)(src + 12);
            s16x8 h0, h1;
            h0[0]=(short)f2bf(v0[0]); h0[1]=(short)f2bf(v0[1]); h0[2]=(short)f2bf(v0[2]); h0[3]=(short)f2bf(v0[3]);
            h0[4]=(short)f2bf(v1[0]); h0[5]=(short)f2bf(v1[1]); h0[6]=(short)f2bf(v1[2]); h0[7]=(short)f2bf(v1[3]);
            h1[0]=(short)f2bf(v2[0]); h1[1]=(short)f2bf(v2[1]); h1[2]=(short)f2bf(v2[2]); h1[3]=(short)f2bf(v2[3]);
            h1[4]=(short)f2bf(v3[0]); h1[5]=(short)f2bf(v3[1]); h1[6]=(short)f2bf(v3[2]); h1[7]=(short)f2bf(v3[3]);
            int off = ar * 128 + aq * 32;
            *(s16x8*)((char*)As + swz(off))      = h0;
            *(s16x8*)((char*)As + swz(off + 16)) = h1;
        }
        {   // stage B (already bf16, K-major)
            const unsigned short* src = wT + (size_t)(n0 + bn) * 256 + ks + bh * 32;
            s16x8 b0 = *(const s16x8*)(src + 0);
            s16x8 b1 = *(const s16x8*)(src + 8);
            s16x8 b2 = *(const s16x8*)(src + 16);
            s16x8 b3 = *(const s16x8*)(src + 24);
            int off = bn * 128 + bh * 64;
            *(s16x8*)((char*)Bs + swz(off))      = b0;
            *(s16x8*)((char*)Bs + swz(off + 16)) = b1;
            *(s16x8*)((char*)Bs + swz(off + 32)) = b2;
            *(s16x8*)((char*)Bs + swz(off + 48)) = b3;
        }
        __syncthreads();
        #pragma unroll
        for (int kc = 0; kc < 2; ++kc) {
            s16x8 af[4], bfr[4];
            #pragma unroll
            for (int i = 0; i < 4; ++i) {
                int off = (wm * 64 + i * 16 + lr) * 128 + kc * 64 + lk * 16;
                af[i] = *(const s16x8*)((const char*)As + swz(off));
            }
            #pragma unroll
            for (int i = 0; i < 4; ++i) {
                int off = (wn * 64 + i * 16 + lr) * 128 + kc * 64 + lk * 16;
                bfr[i] = *(const s16x8*)((const char*)Bs + swz(off));
            }
            #pragma unroll
            for (int i = 0; i < 4; ++i)
                #pragma unroll
                for (int j = 0; j < 4; ++j)
                    acc[i][j] = __builtin_amdgcn_mfma_f32_16x16x32_bf16(af[i], bfr[j], acc[i][j], 0, 0, 0);
        }
        __syncthreads();
    }
    #pragma unroll
    for (int i = 0; i < 4; ++i) {
        const int mg = m0 + wm * 64 + i * 16 + lk * 4;
        #pragma unroll
        for (int j = 0; j < 4; ++j) {
            const int ng = n0 + wn * 64 + j * 16 + lr;
            float bias = (ng < 256) ? qb[ng] : ((ng < 512) ? 0.f : vb[ng - 512]);
            #pragma unroll
            for (int e = 0; e < 4; ++e)
                qkv[(size_t)(mg + e) * 768 + ng] =
                    __builtin_bit_cast(unsigned short, (_Float16)(acc[i][j][e] + bias));
        }
    }
}

// ------------------------------------------------- fused conv + attention ----
// R10 structure: 256 threads, lane owns channel pair (c, c+16); 16 lanes
// per (head, pixel); 2 pixels concurrent (g = t>>7); 8 iterations.
// Conv: 81 v_pk_fma_f16 (identity weights are exactly 1.0 in dk input).
// Products: fdot2.  Reduce: 16 lanes, 4 DPP stages.
// Interior blocks (87%) skip the oob-mask logic (block-uniform branch).

template <int CTRL>
DEVINL float dpp_add(float x) {
    int r = __builtin_amdgcn_update_dpp(0, __builtin_bit_cast(int, x),
                                        CTRL, 0xF, 0xF, true);
    return x + __builtin_bit_cast(float, r);
}
DEVINL float red16(float x) {
    x = dpp_add<0xB1>(x);   // quad_perm [1,0,3,2]  : xor1
    x = dpp_add<0x4E>(x);   // quad_perm [2,3,0,1]  : xor2
    x = dpp_add<0x141>(x);  // row_half_mirror      : 8-group
    x = dpp_add<0x140>(x);  // row_mirror           : 16-group
    return x;
}

__launch_bounds__(256, 1)
__global__ void k_attn(const unsigned short* __restrict__ qkv,
                       const unsigned int* __restrict__ dkw2,
                       const float* __restrict__ relb,
                       const float* __restrict__ escale,
                       unsigned short* __restrict__ att) {
    __shared__ __align__(16) unsigned int ksh[36 * 128];  // k pairs (c, c+16)
    __shared__ __align__(16) unsigned int vsh[36 * 128];  // v pairs
    __shared__ __align__(16) unsigned int qsh[16 * 128];  // q pairs
    const int t = threadIdx.x;
    const int g = t >> 7;          // pixel half
    const int pr = t & 127;        // pair index = head*16 + ci
    const int head = pr >> 4;
    const int w0 = blockIdx.x * 4, h0 = blockIdx.y * 4, b = blockIdx.z;
    const bool interior = (blockIdx.x > 0) & (blockIdx.x < 15) &
                          (blockIdx.y > 0) & (blockIdx.y < 15);

    unsigned int wk[81];           // weight pairs (w_c, w_c+16) per l=ij*9+m
    #pragma unroll
    for (int l = 0; l < 81; ++l) wk[l] = dkw2[l * 128 + pr];
    float rb[9];
    #pragma unroll
    for (int m = 0; m < 9; ++m) rb[m] = relb[head * 9 + m];
    const float es2 = escale[head];          // exp(scale)*log2e

    // stage k/v halo pairs: 36 px x 16 units (unit = data-head*2 + half)
    for (int idx = t; idx < 576; idx += 256) {
        int hp = idx >> 4, u = idx & 15;
        int hh = u >> 1, half = u & 1;
        int cA = hh * 32 + half * 8;
        int hy = h0 - 1 + hp / 6, hx = w0 - 1 + hp % 6;
        i32x4 kA = {0,0,0,0}, kB = {0,0,0,0}, vA = {0,0,0,0}, vB = {0,0,0,0};
        if ((unsigned)hy < 64u && (unsigned)hx < 64u) {
            const unsigned short* base = qkv + ((size_t)((b * 64 + hy) * 64 + hx)) * 768;
            kA = *(const i32x4*)(base + 256 + cA);
            kB = *(const i32x4*)(base + 256 + cA + 16);
            vA = *(const i32x4*)(base + 512 + cA);
            vB = *(const i32x4*)(base + 512 + cA + 16);
        }
        i32x4 kp0, kp1, vp0, vp1;
        #pragma unroll
        for (int e = 0; e < 4; ++e) {
            unsigned klo = __builtin_amdgcn_perm((unsigned)kB[e], (unsigned)kA[e], 0x05040100u);
            unsigned khi = __builtin_amdgcn_perm((unsigned)kB[e], (unsigned)kA[e], 0x07060302u);
            unsigned vlo = __builtin_amdgcn_perm((unsigned)vB[e], (unsigned)vA[e], 0x05040100u);
            unsigned vhi = __builtin_amdgcn_perm((unsigned)vB[e], (unsigned)vA[e], 0x07060302u);
            if (e < 2) {
                kp0[2*e] = (int)klo; kp0[2*e+1] = (int)khi;
                vp0[2*e] = (int)vlo; vp0[2*e+1] = (int)vhi;
            } else {
                kp1[2*(e-2)] = (int)klo; kp1[2*(e-2)+1] = (int)khi;
                vp1[2*(e-2)] = (int)vlo; vp1[2*(e-2)+1] = (int)vhi;
            }
        }
        int pi = hp * 128 + hh * 16 + half * 8;
        *(i32x4*)(ksh + pi)     = kp0;
        *(i32x4*)(ksh + pi + 4) = kp1;
        *(i32x4*)(vsh + pi)     = vp0;
        *(i32x4*)(vsh + pi + 4) = vp1;
    }
    // stage q pairs: exactly one unit per thread (16 px x 16 units)
    {
        int px_s = t >> 4, u = t & 15;
        int hh = u >> 1, half = u & 1;
        int cA = hh * 32 + half * 8;
        int iy = h0 + (px_s >> 2), ix = w0 + (px_s & 3);
        const unsigned short* base = qkv + ((size_t)((b * 64 + iy) * 64 + ix)) * 768;
        i32x4 qA = *(const i32x4*)(base + cA);
        i32x4 qB = *(const i32x4*)(base + cA + 16);
        i32x4 qp0, qp1;
        #pragma unroll
        for (int e = 0; e < 4; ++e) {
            unsigned lo = __builtin_amdgcn_perm((unsigned)qB[e], (unsigned)qA[e], 0x05040100u);
            unsigned hi = __builtin_amdgcn_perm((unsigned)qB[e], (unsigned)qA[e], 0x07060302u);
            if (e < 2) { qp0[2*e] = (int)lo; qp0[2*e+1] = (int)hi; }
            else       { qp1[2*(e-2)] = (int)lo; qp1[2*(e-2)+1] = (int)hi; }
        }
        int pi = px_s * 128 + hh * 16 + half * 8;
        *(i32x4*)(qsh + pi)     = qp0;
        *(i32x4*)(qsh + pi + 4) = qp1;
    }
    __syncthreads();

    #pragma unroll 1
    for (int it = 0; it < 8; ++it) {
        const int p = it * 2 + g;
        const int py = p >> 2, px = p & 3;
        const int iy = h0 + py, ix = w0 + px;
        const size_t pix = (size_t)((b * 64 + iy) * 64 + ix);
        const h2 q2 = __builtin_bit_cast(h2, qsh[p * 128 + pr]);

        h2 ki[9], vi[9];
        #pragma unroll
        for (int ij = 0; ij < 9; ++ij) {
            int hp = (py + ij / 3) * 6 + (px + ij % 3);
            ki[ij] = __builtin_bit_cast(h2, ksh[hp * 128 + pr]);
            vi[ij] = __builtin_bit_cast(h2, vsh[hp * 128 + pr]);
        }
        // conv: all 81 taps (identity positions hold exactly 1.0)
        h2 ka[9], va[9];
        #pragma unroll
        for (int m = 0; m < 9; ++m) {
            h2 w = __builtin_bit_cast(h2, wk[m]);          // ij = 0 row
            ka[m] = ki[0] * w;
            va[m] = vi[0] * w;
        }
        #pragma unroll
        for (int ij = 1; ij < 9; ++ij)
            #pragma unroll
            for (int m = 0; m < 9; ++m) {
                h2 w = __builtin_bit_cast(h2, wk[ij * 9 + m]);
                ka[m] = __builtin_elementwise_fma(ki[ij], w, ka[m]);
                va[m] = __builtin_elementwise_fma(vi[ij], w, va[m]);
            }

        float red[19];
        red[0] = fdot2f(q2, q2, 0.f);
        #pragma unroll
        for (int m = 0; m < 9; ++m) {
            red[1 + m]  = fdot2f(q2, ka[m], 0.f);
            red[10 + m] = fdot2f(ka[m], ka[m], 0.f);
        }
        #pragma unroll
        for (int i = 0; i < 19; ++i) red[i] = red16(red[i]);

        const float rq = __builtin_amdgcn_rsqf(fmaxf(red[0], 1.55e-5f)) * es2;
        float e[9], sum = 0.f;
        if (interior) {
            #pragma unroll
            for (int m = 0; m < 9; ++m) {
                float rk = __builtin_amdgcn_rsqf(fmaxf(red[10 + m], 1.55e-5f));
                float a = red[1 + m] * rq * rk + rb[m];
                e[m] = fexp2(a);
                sum += e[m];
            }
        } else {
            const bool yt = (iy == 0), yb = (iy == 63), xl = (ix == 0), xr = (ix == 63);
            const float NEG = -144.2695040888963f;  // -100*log2e
            #pragma unroll
            for (int m = 0; m < 9; ++m) {
                float rk = __builtin_amdgcn_rsqf(fmaxf(red[10 + m], 1.55e-5f));
                int dy = m / 3 - 1, dx = m % 3 - 1;
                bool oob = (dy < 0 && yt) || (dy > 0 && yb) || (dx < 0 && xl) || (dx > 0 && xr);
                float a = red[1 + m] * rq * rk + rb[m] + (oob ? NEG : 0.f);
                e[m] = fexp2(a);
                sum += e[m];
            }
        }
        const float rs = __builtin_amdgcn_rcpf(sum);
        h2 o2 = {(_Float16)0.f, (_Float16)0.f};
        #pragma unroll
        for (int m = 0; m < 9; ++m) {
            _Float16 ph = (_Float16)(e[m] * rs);   // p in [0,1] -> f16 safe
            h2 pb2 = {ph, ph};
            o2 = __builtin_elementwise_fma(va[m], pb2, o2);
        }
        // pair-ordered att row: dword pr holds (att_c, att_c+16)
        *(unsigned int*)(att + pix * 256 + pr * 2) = __builtin_bit_cast(unsigned int, o2);
    }
}

// ------------------------------------------------------------- proj GEMM ----
__launch_bounds__(512, 1)
__global__ void k_proj_gemm(const unsigned short* __restrict__ attin,
                            const unsigned short* __restrict__ pT,
                            const float* __restrict__ pb,
                            float* __restrict__ out) {
    __shared__ __align__(16) unsigned short As[128 * 64];
    __shared__ __align__(16) unsigned short Bs[256 * 64];
    const int t = threadIdx.x;
    const int m0 = blockIdx.x * 128;
    const int wid = t >> 6, lane = t & 63;
    const int wm = wid >> 2, wn = wid & 3;
    const int lr = lane & 15, lk = lane >> 4;
    const int ar = t >> 2, aq = t & 3;
    const int bn = t >> 1, bh = t & 1;
    f32x4 acc[4][4] = {};

    for (int ks = 0; ks < 256; ks += 64) {
        {   // stage A (f16 rows of att, pair-permuted K — matches pT)
            const unsigned short* src = attin + (size_t)(m0 + ar) * 256 + ks + aq * 16;
            s16x8 h0 = *(const s16x8*)(src + 0);
            s16x8 h1 = *(const s16x8*)(src + 8);
            int off = ar * 128 + aq * 32;
            *(s16x8*)((char*)As + swz(off))      = h0;
            *(s16x8*)((char*)As + swz(off + 16)) = h1;
        }
        {   // stage B (f16)
            const unsigned short* src = pT + (size_t)bn * 256 + ks + bh * 32;
            s16x8 b0 = *(const s16x8*)(src + 0);
            s16x8 b1 = *(const s16x8*)(src + 8);
            s16x8 b2 = *(const s16x8*)(src + 16);
            s16x8 b3 = *(const s16x8*)(src + 24);
            int off = bn * 128 + bh * 64;
            *(s16x8*)((char*)Bs + swz(off))      = b0;
            *(s16x8*)((char*)Bs + swz(off + 16)) = b1;
            *(s16x8*)((char*)Bs + swz(off + 32)) = b2;
            *(s16x8*)((char*)Bs + swz(off + 48)) = b3;
        }
        __syncthreads();
        #pragma unroll
        for (int kc = 0; kc < 2; ++kc) {
            s16x8 af[4], bfr[4];
            #pragma unroll
            for (int i = 0; i < 4; ++i) {
                int off = (wm * 64 + i * 16 + lr) * 128 + kc * 64 + lk * 16;
                af[i] = *(const s16x8*)((const char*)As + swz(off));
            }
            #pragma unroll
            for (int i = 0; i < 4; ++i) {
                int off = (wn * 64 + i * 16 + lr) * 128 + kc * 64 + lk * 16;
                bfr[i] = *(const s16x8*)((const char*)Bs + swz(off));
            }
            #pragma unroll
            for (int i = 0; i < 4; ++i)
                #pragma unroll
                for (int j = 0; j < 4; ++j)
                    acc[i][j] = __builtin_amdgcn_mfma_f32_16x16x32_f16(af[i], bfr[j], acc[i][j], 0, 0, 0);
        }
        __syncthreads();
    }
    #pragma unroll
    for (int i = 0; i < 4; ++i) {
        const int mg = m0 + wm * 64 + i * 16 + lk * 4;
        #pragma unroll
        for (int j = 0; j < 4; ++j) {
            const int ng = wn * 64 + j * 16 + lr;
            const float bias = pb[ng];
            #pragma unroll
            for (int e = 0; e < 4; ++e)
                out[(size_t)(mg + e) * 256 + ng] = acc[i][j][e] + bias;
        }
    }
}

// ----------------------------------------------------------------- launch ----
extern "C" void kernel_launch(void* const* d_in, const int* in_sizes, int n_in,
                              void* d_out, int out_size, void* d_ws, size_t ws_size,
                              hipStream_t stream) {
    const float* x  = (const float*)d_in[0];
    const float* wq = (const float*)d_in[1];
    const float* qb = (const float*)d_in[2];
    const float* vb = (const float*)d_in[3];
    const float* dk = (const float*)d_in[4];
    const float* sc = (const float*)d_in[5];
    const float* w1 = (const float*)d_in[6];
    const float* b1 = (const float*)d_in[7];
    const float* w2 = (const float*)d_in[8];
    const float* pw = (const float*)d_in[9];
    const float* pb = (const float*)d_in[10];
    float* out = (float*)d_out;

    char* ws = (char*)d_ws;
    unsigned short* qkv  = (unsigned short*)(ws + 0);          // 50,331,648 B (f16)
    unsigned short* att  = (unsigned short*)(ws + 50331648);   // 16,777,216 B (f16, pair-order)
    unsigned int*   dkw2 = (unsigned int*)(ws + 67108864);     //     41,472 B (81 x 128 words)
    unsigned short* wT   = (unsigned short*)(ws + 67150336);   //    393,216 B (bf16)
    unsigned short* pT   = (unsigned short*)(ws + 67543552);   //    131,072 B (f16, permuted)
    float*          rlb  = (float*)(ws + 67674624);            //        288 B
    float*          esc  = (float*)(ws + 67674912);            //         32 B

    // k_pre: block 0 = setup; blocks 1..474 = transpose (272,512 items / 576)
    hipLaunchKernelGGL(k_pre, dim3(475), dim3(576), 0, stream,
                       sc, w1, b1, w2, dk, wq, pw, rlb, esc, dkw2, wT, pT);
    hipLaunchKernelGGL(k_qkv_gemm, dim3(768), dim3(512), 0, stream, x, wT, qb, vb, qkv);
    hipLaunchKernelGGL(k_attn, dim3(16, 16, 8), dim3(256), 0, stream, qkv, dkw2, rlb, esc, att);
    hipLaunchKernelGGL(k_proj_gemm, dim3(256), dim3(512), 0, stream, att, pT, pb, out);
}

// Round 15
// 97.745 us; speedup vs baseline: 1.0970x; 1.0970x over previous
//
#include <hip/hip_runtime.h>
#include <hip/hip_bf16.h>
#include <cstdint>
#include <cstddef>

// SlideAttention fused pipeline for MI355X (gfx950).
// B=8, H=W=64, C=256, HEADS=8, U=32, WIN=3 (9 taps), CPB=512.
//
// R15 = 4-channels/lane k_attn: lane owns pair-dwords prA=head*16+li and
// prB=prA+8 (li in 0..7); 8 lanes per (head,pixel), 4 concurrent pixels,
// 4 iterations. Reduction shrinks to 3 DPP stages and the replicated
// softmax/logit block amortizes over 2x channels. Staging layout identical.

typedef __attribute__((ext_vector_type(4))) float f32x4;
typedef __attribute__((ext_vector_type(8))) short s16x8;
typedef __attribute__((ext_vector_type(4))) int   i32x4;
typedef _Float16 h2 __attribute__((ext_vector_type(2)));

#define DEVINL __device__ __forceinline__

DEVINL unsigned short f2bf(float f) {  // RNE, finite inputs only
    unsigned int u = __builtin_bit_cast(unsigned int, f);
    u += 0x7FFFu + ((u >> 16) & 1u);
    return (unsigned short)(u >> 16);
}
// LDS xor-swizzle for GEMM tiles (rows 128 B)
DEVINL int swz(int off) { return off ^ ((off >> 3) & 0x70); }

DEVINL float fexp2(float x) {
#if __has_builtin(__builtin_amdgcn_exp2f)
    return __builtin_amdgcn_exp2f(x);
#else
    return exp2f(x);
#endif
}
DEVINL float fdot2f(h2 a, h2 b, float c) {
#if __has_builtin(__builtin_amdgcn_fdot2)
    return __builtin_amdgcn_fdot2(a, b, c, false);
#else
    return fmaf((float)a.x, (float)b.x, fmaf((float)a.y, (float)b.y, c));
#endif
}

// ------------------------------------------------------- pre (setup+tr) ----
// 576 threads. Block 0: CPB MLP rel_bias + exp(scale) (log2-domain).
// Blocks 1..: dk -> dkw2 (l*128+pr) pairs; w_qkv -> wT bf16; proj_w -> pT
// f16 (pair-permuted).
__global__ void k_pre(const float* __restrict__ scale,
                      const float* __restrict__ w1,
                      const float* __restrict__ b1,
                      const float* __restrict__ w2,
                      const float* __restrict__ dk,
                      const float* __restrict__ wq,
                      const float* __restrict__ pw,
                      float* __restrict__ relb,
                      float* __restrict__ escale,
                      unsigned int* __restrict__ dkw2,
                      unsigned short* __restrict__ wT,
                      unsigned short* __restrict__ pT) {
    const int t = threadIdx.x;
    if (blockIdx.x == 0) {
        __shared__ float hbuf[512 * 9];
        __shared__ float part[8][72];
        const float LOG2E = 1.4426950408889634f;
        if (t < 512) {
            float wa = w1[t], wb = w1[512 + t], bb = b1[t];
            #pragma unroll
            for (int m = 0; m < 9; ++m) {
                float dy = (float)(m / 3 - 1), dx = (float)(m % 3 - 1);
                const float il8 = 0.48089834696298783f; // 1/ln(8)
                float r0 = (dy > 0.f ? 1.f : (dy < 0.f ? -1.f : 0.f)) * log1pf(fabsf(dy)) * il8;
                float r1 = (dx > 0.f ? 1.f : (dx < 0.f ? -1.f : 0.f)) * log1pf(fabsf(dx)) * il8;
                hbuf[t * 9 + m] = fmaxf(r0 * wa + r1 * wb + bb, 0.f);
            }
        }
        __syncthreads();
        {
            int chunk = t / 72, mh = t % 72;
            int m = mh / 8, head = mh % 8;
            float acc = 0.f;
            #pragma unroll 8
            for (int j = chunk * 64; j < chunk * 64 + 64; ++j)
                acc = fmaf(hbuf[j * 9 + m], w2[j * 8 + head], acc);
            part[chunk][mh] = acc;
        }
        __syncthreads();
        if (t < 72) {
            int m = t / 8, head = t % 8;
            float acc = 0.f;
            #pragma unroll
            for (int ch = 0; ch < 8; ++ch) acc += part[ch][t];
            relb[head * 9 + m] = 16.f / (1.f + expf(-acc)) * LOG2E;
        } else if (t < 80) {
            escale[t - 72] = expf(scale[t - 72]) * LOG2E;
        }
        return;
    }
    int i = (blockIdx.x - 1) * 576 + t;
    if (i < 10368) {   // dkw2[l*128+pr] = (f16 dk[tap][c][m], f16 dk[tap][c+16][m])
        int l = i >> 7, pr = i & 127;
        int tap = l / 9, m = l % 9;
        int c = (pr >> 4) * 32 + (pr & 15);
        float f0 = dk[(tap * 256 + c) * 9 + m];
        float f1 = dk[(tap * 256 + c + 16) * 9 + m];
        unsigned short h0 = __builtin_bit_cast(unsigned short, (_Float16)f0);
        unsigned short h1 = __builtin_bit_cast(unsigned short, (_Float16)f1);
        dkw2[i] = (unsigned int)h0 | ((unsigned int)h1 << 16);
        return;
    }
    int j = i - 10368;
    if (j < 196608) {                   // wT[n*256+k] = bf16(wq[k*768+n])
        int n = j >> 8, k = j & 255;
        wT[j] = f2bf(wq[k * 768 + n]);
        return;
    }
    int p = j - 196608;
    if (p < 65536) {   // pT[n*256+kp] = f16(pw[c(kp)*256+n]), pair-permuted K
        int n = p >> 8, kp = p & 255;
        int head = kp >> 5, tt = kp & 31, ci = tt >> 1, jj = tt & 1;
        int c = head * 32 + ci + 16 * jj;
        pT[p] = __builtin_bit_cast(unsigned short, (_Float16)pw[c * 256 + n]);
    }
}

// ------------------------------------------------------------- qkv GEMM ----
// 768 blocks; XCD-chunked so the 3 N-tiles of one M-tile land on one XCD L2.
__launch_bounds__(512, 1)
__global__ void k_qkv_gemm(const float* __restrict__ x,
                           const unsigned short* __restrict__ wT,
                           const float* __restrict__ qb,
                           const float* __restrict__ vb,
                           unsigned short* __restrict__ qkv) {
    __shared__ __align__(16) unsigned short As[128 * 64];
    __shared__ __align__(16) unsigned short Bs[256 * 64];
    const int orig = blockIdx.x;
    const int tile = (orig & 7) * 96 + (orig >> 3);   // 768 = 8 XCD x 96
    const int m0 = (tile / 3) * 128;
    const int n0 = (tile % 3) * 256;
    const int t = threadIdx.x;
    const int wid = t >> 6, lane = t & 63;
    const int wm = wid >> 2, wn = wid & 3;
    const int lr = lane & 15, lk = lane >> 4;
    const int ar = t >> 2, aq = t & 3;
    const int bn = t >> 1, bh = t & 1;
    f32x4 acc[4][4] = {};

    for (int ks = 0; ks < 256; ks += 64) {
        {   // stage A (f32 -> bf16)
            const float* src = x + (size_t)(m0 + ar) * 256 + ks + aq * 16;
            f32x4 v0 = *(const f32x4*)(src + 0);
            f32x4 v1 = *(const f32x4*)(src + 4);
            f32x4 v2 = *(const f32x4*)(src + 8);
            f32x4 v3 = *(const f32x4*)(src + 12);
            s16x8 h0, h1;
            h0[0]=(short)f2bf(v0[0]); h0[1]=(short)f2bf(v0[1]); h0[2]=(short)f2bf(v0[2]); h0[3]=(short)f2bf(v0[3]);
            h0[4]=(short)f2bf(v1[0]); h0[5]=(short)f2bf(v1[1]); h0[6]=(short)f2bf(v1[2]); h0[7]=(short)f2bf(v1[3]);
            h1[0]=(short)f2bf(v2[0]); h1[1]=(short)f2bf(v2[1]); h1[2]=(short)f2bf(v2[2]); h1[3]=(short)f2bf(v2[3]);
            h1[4]=(short)f2bf(v3[0]); h1[5]=(short)f2bf(v3[1]); h1[6]=(short)f2bf(v3[2]); h1[7]=(short)f2bf(v3[3]);
            int off = ar * 128 + aq * 32;
            *(s16x8*)((char*)As + swz(off))      = h0;
            *(s16x8*)((char*)As + swz(off + 16)) = h1;
        }
        {   // stage B (already bf16, K-major)
            const unsigned short* src = wT + (size_t)(n0 + bn) * 256 + ks + bh * 32;
            s16x8 b0 = *(const s16x8*)(src + 0);
            s16x8 b1 = *(const s16x8*)(src + 8);
            s16x8 b2 = *(const s16x8*)(src + 16);
            s16x8 b3 = *(const s16x8*)(src + 24);
            int off = bn * 128 + bh * 64;
            *(s16x8*)((char*)Bs + swz(off))      = b0;
            *(s16x8*)((char*)Bs + swz(off + 16)) = b1;
            *(s16x8*)((char*)Bs + swz(off + 32)) = b2;
            *(s16x8*)((char*)Bs + swz(off + 48)) = b3;
        }
        __syncthreads();
        #pragma unroll
        for (int kc = 0; kc < 2; ++kc) {
            s16x8 af[4], bfr[4];
            #pragma unroll
            for (int i = 0; i < 4; ++i) {
                int off = (wm * 64 + i * 16 + lr) * 128 + kc * 64 + lk * 16;
                af[i] = *(const s16x8*)((const char*)As + swz(off));
            }
            #pragma unroll
            for (int i = 0; i < 4; ++i) {
                int off = (wn * 64 + i * 16 + lr) * 128 + kc * 64 + lk * 16;
                bfr[i] = *(const s16x8*)((const char*)Bs + swz(off));
            }
            #pragma unroll
            for (int i = 0; i < 4; ++i)
                #pragma unroll
                for (int j = 0; j < 4; ++j)
                    acc[i][j] = __builtin_amdgcn_mfma_f32_16x16x32_bf16(af[i], bfr[j], acc[i][j], 0, 0, 0);
        }
        __syncthreads();
    }
    #pragma unroll
    for (int i = 0; i < 4; ++i) {
        const int mg = m0 + wm * 64 + i * 16 + lk * 4;
        #pragma unroll
        for (int j = 0; j < 4; ++j) {
            const int ng = n0 + wn * 64 + j * 16 + lr;
            float bias = (ng < 256) ? qb[ng] : ((ng < 512) ? 0.f : vb[ng - 512]);
            #pragma unroll
            for (int e = 0; e < 4; ++e)
                qkv[(size_t)(mg + e) * 768 + ng] =
                    __builtin_bit_cast(unsigned short, (_Float16)(acc[i][j][e] + bias));
        }
    }
}

// ------------------------------------------------- fused conv + attention ----
// 4 channels/lane: lane owns pair-dwords prA = head*16+li, prB = prA+8
// (li = t&7).  8 lanes per (head, pixel); 4 concurrent pixels (g = t>>6);
// 4 iterations.  Conv: v_pk_fma_f16 on both dwords; products: nested fdot2;
// reduce: 8 lanes, 3 DPP stages.  Staging layout identical to R10/R14.

template <int CTRL>
DEVINL float dpp_add(float x) {
    int r = __builtin_amdgcn_update_dpp(0, __builtin_bit_cast(int, x),
                                        CTRL, 0xF, 0xF, true);
    return x + __builtin_bit_cast(float, r);
}
DEVINL float red8(float x) {
    x = dpp_add<0xB1>(x);   // quad_perm [1,0,3,2]  : xor1
    x = dpp_add<0x4E>(x);   // quad_perm [2,3,0,1]  : xor2
    x = dpp_add<0x141>(x);  // row_half_mirror      : completes 8-lane sum
    return x;
}

__launch_bounds__(256, 4)
__global__ void k_attn(const unsigned short* __restrict__ qkv,
                       const unsigned int* __restrict__ dkw2,
                       const float* __restrict__ relb,
                       const float* __restrict__ escale,
                       unsigned short* __restrict__ att) {
    __shared__ __align__(16) unsigned int ksh[36 * 128];  // k pairs (c, c+16)
    __shared__ __align__(16) unsigned int vsh[36 * 128];  // v pairs
    __shared__ __align__(16) unsigned int qsh[16 * 128];  // q pairs
    const int t = threadIdx.x;
    const int g = t >> 6;            // pixel slot (0..3)
    const int li = t & 7;            // lane within head-group
    const int head = (t >> 3) & 7;
    const int prA = head * 16 + li;  // dword A: channels (c, c+16)
    const int prB = prA + 8;         // dword B: channels (c+8, c+24)
    const int w0 = blockIdx.x * 4, h0 = blockIdx.y * 4, b = blockIdx.z;

    float rb[9];
    #pragma unroll
    for (int m = 0; m < 9; ++m) rb[m] = relb[head * 9 + m];
    const float es2 = escale[head];          // exp(scale)*log2e

    // stage k/v halo pairs: 36 px x 16 units (unit = data-head*2 + half)
    for (int idx = t; idx < 576; idx += 256) {
        int hp = idx >> 4, u = idx & 15;
        int hh = u >> 1, half = u & 1;
        int cA = hh * 32 + half * 8;
        int hy = h0 - 1 + hp / 6, hx = w0 - 1 + hp % 6;
        i32x4 kA = {0,0,0,0}, kB = {0,0,0,0}, vA = {0,0,0,0}, vB = {0,0,0,0};
        if ((unsigned)hy < 64u && (unsigned)hx < 64u) {
            const unsigned short* base = qkv + ((size_t)((b * 64 + hy) * 64 + hx)) * 768;
            kA = *(const i32x4*)(base + 256 + cA);
            kB = *(const i32x4*)(base + 256 + cA + 16);
            vA = *(const i32x4*)(base + 512 + cA);
            vB = *(const i32x4*)(base + 512 + cA + 16);
        }
        i32x4 kp0, kp1, vp0, vp1;
        #pragma unroll
        for (int e = 0; e < 4; ++e) {
            unsigned klo = __builtin_amdgcn_perm((unsigned)kB[e], (unsigned)kA[e], 0x05040100u);
            unsigned khi = __builtin_amdgcn_perm((unsigned)kB[e], (unsigned)kA[e], 0x07060302u);
            unsigned vlo = __builtin_amdgcn_perm((unsigned)vB[e], (unsigned)vA[e], 0x05040100u);
            unsigned vhi = __builtin_amdgcn_perm((unsigned)vB[e], (unsigned)vA[e], 0x07060302u);
            if (e < 2) {
                kp0[2*e] = (int)klo; kp0[2*e+1] = (int)khi;
                vp0[2*e] = (int)vlo; vp0[2*e+1] = (int)vhi;
            } else {
                kp1[2*(e-2)] = (int)klo; kp1[2*(e-2)+1] = (int)khi;
                vp1[2*(e-2)] = (int)vlo; vp1[2*(e-2)+1] = (int)vhi;
            }
        }
        int pi = hp * 128 + hh * 16 + half * 8;
        *(i32x4*)(ksh + pi)     = kp0;
        *(i32x4*)(ksh + pi + 4) = kp1;
        *(i32x4*)(vsh + pi)     = vp0;
        *(i32x4*)(vsh + pi + 4) = vp1;
    }
    // stage q pairs: exactly one unit per thread (16 px x 16 units)
    {
        int px_s = t >> 4, u = t & 15;
        int hh = u >> 1, half = u & 1;
        int cA = hh * 32 + half * 8;
        int iy = h0 + (px_s >> 2), ix = w0 + (px_s & 3);
        const unsigned short* base = qkv + ((size_t)((b * 64 + iy) * 64 + ix)) * 768;
        i32x4 qA = *(const i32x4*)(base + cA);
        i32x4 qB = *(const i32x4*)(base + cA + 16);
        i32x4 qp0, qp1;
        #pragma unroll
        for (int e = 0; e < 4; ++e) {
            unsigned lo = __builtin_amdgcn_perm((unsigned)qB[e], (unsigned)qA[e], 0x05040100u);
            unsigned hi = __builtin_amdgcn_perm((unsigned)qB[e], (unsigned)qA[e], 0x07060302u);
            if (e < 2) { qp0[2*e] = (int)lo; qp0[2*e+1] = (int)hi; }
            else       { qp1[2*(e-2)] = (int)lo; qp1[2*(e-2)+1] = (int)hi; }
        }
        int pi = px_s * 128 + hh * 16 + half * 8;
        *(i32x4*)(qsh + pi)     = qp0;
        *(i32x4*)(qsh + pi + 4) = qp1;
    }
    __syncthreads();

    #pragma unroll 1
    for (int it = 0; it < 4; ++it) {
        const int p = it * 4 + g;
        const int py = p >> 2, px = p & 3;
        const int iy = h0 + py, ix = w0 + px;
        const size_t pix = (size_t)((b * 64 + iy) * 64 + ix);
        const h2 qA = __builtin_bit_cast(h2, qsh[p * 128 + prA]);
        const h2 qB = __builtin_bit_cast(h2, qsh[p * 128 + prB]);

        // conv: ij-outer, all 81 taps (identity weights are exactly 1.0),
        // inputs read from LDS per-ij, weights streamed from L2.
        h2 kaA[9], kaB[9], vaA[9], vaB[9];
        #pragma unroll
        for (int ij = 0; ij < 9; ++ij) {
            const int hp = (py + ij / 3) * 6 + (px + ij % 3);
            const h2 kiA = __builtin_bit_cast(h2, ksh[hp * 128 + prA]);
            const h2 kiB = __builtin_bit_cast(h2, ksh[hp * 128 + prB]);
            const h2 viA = __builtin_bit_cast(h2, vsh[hp * 128 + prA]);
            const h2 viB = __builtin_bit_cast(h2, vsh[hp * 128 + prB]);
            #pragma unroll
            for (int m = 0; m < 9; ++m) {
                const int l = ij * 9 + m;
                h2 wA = __builtin_bit_cast(h2, dkw2[l * 128 + prA]);
                h2 wB = __builtin_bit_cast(h2, dkw2[l * 128 + prB]);
                if (ij == 0) {
                    kaA[m] = kiA * wA;  kaB[m] = kiB * wB;
                    vaA[m] = viA * wA;  vaB[m] = viB * wB;
                } else {
                    kaA[m] = __builtin_elementwise_fma(kiA, wA, kaA[m]);
                    kaB[m] = __builtin_elementwise_fma(kiB, wB, kaB[m]);
                    vaA[m] = __builtin_elementwise_fma(viA, wA, vaA[m]);
                    vaB[m] = __builtin_elementwise_fma(viB, wB, vaB[m]);
                }
            }
        }

        float red[19];
        red[0] = fdot2f(qA, qA, fdot2f(qB, qB, 0.f));
        #pragma unroll
        for (int m = 0; m < 9; ++m) {
            red[1 + m]  = fdot2f(qA, kaA[m], fdot2f(qB, kaB[m], 0.f));
            red[10 + m] = fdot2f(kaA[m], kaA[m], fdot2f(kaB[m], kaB[m], 0.f));
        }
        #pragma unroll
        for (int i = 0; i < 19; ++i) red[i] = red8(red[i]);

        const float rq = __builtin_amdgcn_rsqf(fmaxf(red[0], 1.55e-5f)) * es2;
        const bool yt = (iy == 0), yb = (iy == 63), xl = (ix == 0), xr = (ix == 63);
        const float NEG = -144.2695040888963f;  // -100*log2e
        float e[9], sum = 0.f;
        #pragma unroll
        for (int m = 0; m < 9; ++m) {
            float rk = __builtin_amdgcn_rsqf(fmaxf(red[10 + m], 1.55e-5f));
            int dy = m / 3 - 1, dx = m % 3 - 1;
            bool oob = (dy < 0 && yt) || (dy > 0 && yb) || (dx < 0 && xl) || (dx > 0 && xr);
            float a = red[1 + m] * rq * rk + rb[m] + (oob ? NEG : 0.f);
            e[m] = fexp2(a);            // f32: range-safe without max-subtract
            sum += e[m];
        }
        const float rs = __builtin_amdgcn_rcpf(sum);
        h2 oA = {(_Float16)0.f, (_Float16)0.f};
        h2 oB = {(_Float16)0.f, (_Float16)0.f};
        #pragma unroll
        for (int m = 0; m < 9; ++m) {
            _Float16 ph = (_Float16)(e[m] * rs);   // p in [0,1] -> f16 safe
            h2 pb2 = {ph, ph};
            oA = __builtin_elementwise_fma(vaA[m], pb2, oA);
            oB = __builtin_elementwise_fma(vaB[m], pb2, oB);
        }
        // pair-ordered att row: dword pr holds (att_c, att_c+16)
        *(unsigned int*)(att + pix * 256 + prA * 2) = __builtin_bit_cast(unsigned int, oA);
        *(unsigned int*)(att + pix * 256 + prB * 2) = __builtin_bit_cast(unsigned int, oB);
    }
}

// ------------------------------------------------------------- proj GEMM ----
__launch_bounds__(512, 1)
__global__ void k_proj_gemm(const unsigned short* __restrict__ attin,
                            const unsigned short* __restrict__ pT,
                            const float* __restrict__ pb,
                            float* __restrict__ out) {
    __shared__ __align__(16) unsigned short As[128 * 64];
    __shared__ __align__(16) unsigned short Bs[256 * 64];
    const int t = threadIdx.x;
    const int m0 = blockIdx.x * 128;
    const int wid = t >> 6, lane = t & 63;
    const int wm = wid >> 2, wn = wid & 3;
    const int lr = lane & 15, lk = lane >> 4;
    const int ar = t >> 2, aq = t & 3;
    const int bn = t >> 1, bh = t & 1;
    f32x4 acc[4][4] = {};

    for (int ks = 0; ks < 256; ks += 64) {
        {   // stage A (f16 rows of att, pair-permuted K — matches pT)
            const unsigned short* src = attin + (size_t)(m0 + ar) * 256 + ks + aq * 16;
            s16x8 h0 = *(const s16x8*)(src + 0);
            s16x8 h1 = *(const s16x8*)(src + 8);
            int off = ar * 128 + aq * 32;
            *(s16x8*)((char*)As + swz(off))      = h0;
            *(s16x8*)((char*)As + swz(off + 16)) = h1;
        }
        {   // stage B (f16)
            const unsigned short* src = pT + (size_t)bn * 256 + ks + bh * 32;
            s16x8 b0 = *(const s16x8*)(src + 0);
            s16x8 b1 = *(const s16x8*)(src + 8);
            s16x8 b2 = *(const s16x8*)(src + 16);
            s16x8 b3 = *(const s16x8*)(src + 24);
            int off = bn * 128 + bh * 64;
            *(s16x8*)((char*)Bs + swz(off))      = b0;
            *(s16x8*)((char*)Bs + swz(off + 16)) = b1;
            *(s16x8*)((char*)Bs + swz(off + 32)) = b2;
            *(s16x8*)((char*)Bs + swz(off + 48)) = b3;
        }
        __syncthreads();
        #pragma unroll
        for (int kc = 0; kc < 2; ++kc) {
            s16x8 af[4], bfr[4];
            #pragma unroll
            for (int i = 0; i < 4; ++i) {
                int off = (wm * 64 + i * 16 + lr) * 128 + kc * 64 + lk * 16;
                af[i] = *(const s16x8*)((const char*)As + swz(off));
            }
            #pragma unroll
            for (int i = 0; i < 4; ++i) {
                int off = (wn * 64 + i * 16 + lr) * 128 + kc * 64 + lk * 16;
                bfr[i] = *(const s16x8*)((const char*)Bs + swz(off));
            }
            #pragma unroll
            for (int i = 0; i < 4; ++i)
                #pragma unroll
                for (int j = 0; j < 4; ++j)
                    acc[i][j] = __builtin_amdgcn_mfma_f32_16x16x32_f16(af[i], bfr[j], acc[i][j], 0, 0, 0);
        }
        __syncthreads();
    }
    #pragma unroll
    for (int i = 0; i < 4; ++i) {
        const int mg = m0 + wm * 64 + i * 16 + lk * 4;
        #pragma unroll
        for (int j = 0; j < 4; ++j) {
            const int ng = wn * 64 + j * 16 + lr;
            const float bias = pb[ng];
            #pragma unroll
            for (int e = 0; e < 4; ++e)
                out[(size_t)(mg + e) * 256 + ng] = acc[i][j][e] + bias;
        }
    }
}

// ----------------------------------------------------------------- launch ----
extern "C" void kernel_launch(void* const* d_in, const int* in_sizes, int n_in,
                              void* d_out, int out_size, void* d_ws, size_t ws_size,
                              hipStream_t stream) {
    const float* x  = (const float*)d_in[0];
    const float* wq = (const float*)d_in[1];
    const float* qb = (const float*)d_in[2];
    const float* vb = (const float*)d_in[3];
    const float* dk = (const float*)d_in[4];
    const float* sc = (const float*)d_in[5];
    const float* w1 = (const float*)d_in[6];
    const float* b1 = (const float*)d_in[7];
    const float* w2 = (const float*)d_in[8];
    const float* pw = (const float*)d_in[9];
    const float* pb = (const float*)d_in[10];
    float* out = (float*)d_out;

    char* ws = (char*)d_ws;
    unsigned short* qkv  = (unsigned short*)(ws + 0);          // 50,331,648 B (f16)
    unsigned short* att  = (unsigned short*)(ws + 50331648);   // 16,777,216 B (f16, pair-order)
    unsigned int*   dkw2 = (unsigned int*)(ws + 67108864);     //     41,472 B (81 x 128 words)
    unsigned short* wT   = (unsigned short*)(ws + 67150336);   //    393,216 B (bf16)
    unsigned short* pT   = (unsigned short*)(ws + 67543552);   //    131,072 B (f16, permuted)
    float*          rlb  = (float*)(ws + 67674624);            //        288 B
    float*          esc  = (float*)(ws + 67674912);            //         32 B

    // k_pre: block 0 = setup; blocks 1..474 = transpose (272,512 items / 576)
    hipLaunchKernelGGL(k_pre, dim3(475), dim3(576), 0, stream,
                       sc, w1, b1, w2, dk, wq, pw, rlb, esc, dkw2, wT, pT);
    hipLaunchKernelGGL(k_qkv_gemm, dim3(768), dim3(512), 0, stream, x, wT, qb, vb, qkv);
    hipLaunchKernelGGL(k_attn, dim3(16, 16, 8), dim3(256), 0, stream, qkv, dkw2, rlb, esc, att);
    hipLaunchKernelGGL(k_proj_gemm, dim3(256), dim3(512), 0, stream, att, pT, pb, out);
}

// Round 17
// 96.805 us; speedup vs baseline: 1.1077x; 1.0097x over previous
//
#include <hip/hip_runtime.h>
#include <hip/hip_bf16.h>
#include <cstdint>
#include <cstddef>

// SlideAttention fused pipeline for MI355X (gfx950).
// B=8, H=W=64, C=256, HEADS=8, U=32, WIN=3 (9 taps), CPB=512.
//
// R17 = R15 (passing, 54.5us k_attn) + LDS bank swizzle sg(d)=d^((d>>2)&0x18)
// applied to EVERY ksh/vsh/qsh write and read (same involution both sides).
// Lane->channel mapping, weights, att writes byte-identical to R15.
// Fixes the 4-way read conflict (64 lanes -> 16 banks) to 2-way (free).

typedef __attribute__((ext_vector_type(4))) float f32x4;
typedef __attribute__((ext_vector_type(8))) short s16x8;
typedef __attribute__((ext_vector_type(4))) int   i32x4;
typedef _Float16 h2 __attribute__((ext_vector_type(2)));

#define DEVINL __device__ __forceinline__

DEVINL unsigned short f2bf(float f) {  // RNE, finite inputs only
    unsigned int u = __builtin_bit_cast(unsigned int, f);
    u += 0x7FFFu + ((u >> 16) & 1u);
    return (unsigned short)(u >> 16);
}
// LDS xor-swizzle for GEMM tiles (rows 128 B)
DEVINL int swz(int off) { return off ^ ((off >> 3) & 0x70); }
// k_attn LDS dword-index swizzle: XOR head-bits (5-6) into bank bits (3-4).
// Involution; constant across each 8-dword staging unit.
DEVINL int sg(int d) { return d ^ ((d >> 2) & 0x18); }

DEVINL float fexp2(float x) {
#if __has_builtin(__builtin_amdgcn_exp2f)
    return __builtin_amdgcn_exp2f(x);
#else
    return exp2f(x);
#endif
}
DEVINL float fdot2f(h2 a, h2 b, float c) {
#if __has_builtin(__builtin_amdgcn_fdot2)
    return __builtin_amdgcn_fdot2(a, b, c, false);
#else
    return fmaf((float)a.x, (float)b.x, fmaf((float)a.y, (float)b.y, c));
#endif
}

// ------------------------------------------------------- pre (setup+tr) ----
// 576 threads. Block 0: CPB MLP rel_bias + exp(scale) (log2-domain).
// Blocks 1..: dk -> dkw2 (l*128+pr) pairs; w_qkv -> wT bf16; proj_w -> pT
// f16 (pair-permuted).
__global__ void k_pre(const float* __restrict__ scale,
                      const float* __restrict__ w1,
                      const float* __restrict__ b1,
                      const float* __restrict__ w2,
                      const float* __restrict__ dk,
                      const float* __restrict__ wq,
                      const float* __restrict__ pw,
                      float* __restrict__ relb,
                      float* __restrict__ escale,
                      unsigned int* __restrict__ dkw2,
                      unsigned short* __restrict__ wT,
                      unsigned short* __restrict__ pT) {
    const int t = threadIdx.x;
    if (blockIdx.x == 0) {
        __shared__ float hbuf[512 * 9];
        __shared__ float part[8][72];
        const float LOG2E = 1.4426950408889634f;
        if (t < 512) {
            float wa = w1[t], wb = w1[512 + t], bb = b1[t];
            #pragma unroll
            for (int m = 0; m < 9; ++m) {
                float dy = (float)(m / 3 - 1), dx = (float)(m % 3 - 1);
                const float il8 = 0.48089834696298783f; // 1/ln(8)
                float r0 = (dy > 0.f ? 1.f : (dy < 0.f ? -1.f : 0.f)) * log1pf(fabsf(dy)) * il8;
                float r1 = (dx > 0.f ? 1.f : (dx < 0.f ? -1.f : 0.f)) * log1pf(fabsf(dx)) * il8;
                hbuf[t * 9 + m] = fmaxf(r0 * wa + r1 * wb + bb, 0.f);
            }
        }
        __syncthreads();
        {
            int chunk = t / 72, mh = t % 72;
            int m = mh / 8, head = mh % 8;
            float acc = 0.f;
            #pragma unroll 8
            for (int j = chunk * 64; j < chunk * 64 + 64; ++j)
                acc = fmaf(hbuf[j * 9 + m], w2[j * 8 + head], acc);
            part[chunk][mh] = acc;
        }
        __syncthreads();
        if (t < 72) {
            int m = t / 8, head = t % 8;
            float acc = 0.f;
            #pragma unroll
            for (int ch = 0; ch < 8; ++ch) acc += part[ch][t];
            relb[head * 9 + m] = 16.f / (1.f + expf(-acc)) * LOG2E;
        } else if (t < 80) {
            escale[t - 72] = expf(scale[t - 72]) * LOG2E;
        }
        return;
    }
    int i = (blockIdx.x - 1) * 576 + t;
    if (i < 10368) {   // dkw2[l*128+pr] = (f16 dk[tap][c][m], f16 dk[tap][c+16][m])
        int l = i >> 7, pr = i & 127;
        int tap = l / 9, m = l % 9;
        int c = (pr >> 4) * 32 + (pr & 15);
        float f0 = dk[(tap * 256 + c) * 9 + m];
        float f1 = dk[(tap * 256 + c + 16) * 9 + m];
        unsigned short h0 = __builtin_bit_cast(unsigned short, (_Float16)f0);
        unsigned short h1 = __builtin_bit_cast(unsigned short, (_Float16)f1);
        dkw2[i] = (unsigned int)h0 | ((unsigned int)h1 << 16);
        return;
    }
    int j = i - 10368;
    if (j < 196608) {                   // wT[n*256+k] = bf16(wq[k*768+n])
        int n = j >> 8, k = j & 255;
        wT[j] = f2bf(wq[k * 768 + n]);
        return;
    }
    int p = j - 196608;
    if (p < 65536) {   // pT[n*256+kp] = f16(pw[c(kp)*256+n]), pair-permuted K
        int n = p >> 8, kp = p & 255;
        int head = kp >> 5, tt = kp & 31, ci = tt >> 1, jj = tt & 1;
        int c = head * 32 + ci + 16 * jj;
        pT[p] = __builtin_bit_cast(unsigned short, (_Float16)pw[c * 256 + n]);
    }
}

// ------------------------------------------------------------- qkv GEMM ----
// 768 blocks; XCD-chunked so the 3 N-tiles of one M-tile land on one XCD L2.
__launch_bounds__(512, 1)
__global__ void k_qkv_gemm(const float* __restrict__ x,
                           const unsigned short* __restrict__ wT,
                           const float* __restrict__ qb,
                           const float* __restrict__ vb,
                           unsigned short* __restrict__ qkv) {
    __shared__ __align__(16) unsigned short As[128 * 64];
    __shared__ __align__(16) unsigned short Bs[256 * 64];
    const int orig = blockIdx.x;
    const int tile = (orig & 7) * 96 + (orig >> 3);   // 768 = 8 XCD x 96
    const int m0 = (tile / 3) * 128;
    const int n0 = (tile % 3) * 256;
    const int t = threadIdx.x;
    const int wid = t >> 6, lane = t & 63;
    const int wm = wid >> 2, wn = wid & 3;
    const int lr = lane & 15, lk = lane >> 4;
    const int ar = t >> 2, aq = t & 3;
    const int bn = t >> 1, bh = t & 1;
    f32x4 acc[4][4] = {};

    for (int ks = 0; ks < 256; ks += 64) {
        {   // stage A (f32 -> bf16)
            const float* src = x + (size_t)(m0 + ar) * 256 + ks + aq * 16;
            f32x4 v0 = *(const f32x4*)(src + 0);
            f32x4 v1 = *(const f32x4*)(src + 4);
            f32x4 v2 = *(const f32x4*)(src + 8);
            f32x4 v3 = *(const f32x4*)(src + 12);
            s16x8 h0, h1;
            h0[0]=(short)f2bf(v0[0]); h0[1]=(short)f2bf(v0[1]); h0[2]=(short)f2bf(v0[2]); h0[3]=(short)f2bf(v0[3]);
            h0[4]=(short)f2bf(v1[0]); h0[5]=(short)f2bf(v1[1]); h0[6]=(short)f2bf(v1[2]); h0[7]=(short)f2bf(v1[3]);
            h1[0]=(short)f2bf(v2[0]); h1[1]=(short)f2bf(v2[1]); h1[2]=(short)f2bf(v2[2]); h1[3]=(short)f2bf(v2[3]);
            h1[4]=(short)f2bf(v3[0]); h1[5]=(short)f2bf(v3[1]); h1[6]=(short)f2bf(v3[2]); h1[7]=(short)f2bf(v3[3]);
            int off = ar * 128 + aq * 32;
            *(s16x8*)((char*)As + swz(off))      = h0;
            *(s16x8*)((char*)As + swz(off + 16)) = h1;
        }
        {   // stage B (already bf16, K-major)
            const unsigned short* src = wT + (size_t)(n0 + bn) * 256 + ks + bh * 32;
            s16x8 b0 = *(const s16x8*)(src + 0);
            s16x8 b1 = *(const s16x8*)(src + 8);
            s16x8 b2 = *(const s16x8*)(src + 16);
            s16x8 b3 = *(const s16x8*)(src + 24);
            int off = bn * 128 + bh * 64;
            *(s16x8*)((char*)Bs + swz(off))      = b0;
            *(s16x8*)((char*)Bs + swz(off + 16)) = b1;
            *(s16x8*)((char*)Bs + swz(off + 32)) = b2;
            *(s16x8*)((char*)Bs + swz(off + 48)) = b3;
        }
        __syncthreads();
        #pragma unroll
        for (int kc = 0; kc < 2; ++kc) {
            s16x8 af[4], bfr[4];
            #pragma unroll
            for (int i = 0; i < 4; ++i) {
                int off = (wm * 64 + i * 16 + lr) * 128 + kc * 64 + lk * 16;
                af[i] = *(const s16x8*)((const char*)As + swz(off));
            }
            #pragma unroll
            for (int i = 0; i < 4; ++i) {
                int off = (wn * 64 + i * 16 + lr) * 128 + kc * 64 + lk * 16;
                bfr[i] = *(const s16x8*)((const char*)Bs + swz(off));
            }
            #pragma unroll
            for (int i = 0; i < 4; ++i)
                #pragma unroll
                for (int j = 0; j < 4; ++j)
                    acc[i][j] = __builtin_amdgcn_mfma_f32_16x16x32_bf16(af[i], bfr[j], acc[i][j], 0, 0, 0);
        }
        __syncthreads();
    }
    #pragma unroll
    for (int i = 0; i < 4; ++i) {
        const int mg = m0 + wm * 64 + i * 16 + lk * 4;
        #pragma unroll
        for (int j = 0; j < 4; ++j) {
            const int ng = n0 + wn * 64 + j * 16 + lr;
            float bias = (ng < 256) ? qb[ng] : ((ng < 512) ? 0.f : vb[ng - 512]);
            #pragma unroll
            for (int e = 0; e < 4; ++e)
                qkv[(size_t)(mg + e) * 768 + ng] =
                    __builtin_bit_cast(unsigned short, (_Float16)(acc[i][j][e] + bias));
        }
    }
}

// ------------------------------------------------- fused conv + attention ----
// R15 structure: 4 channels/lane, prA = head*16+li, prB = prA+8 (li = t&7).
// 8 lanes per (head, pixel); 4 concurrent pixels (g = t>>6); 4 iterations.
// LDS addresses pass through sg() on BOTH write and read (bank fix only).
// Reduce: 8 lanes, 3 DPP stages.

template <int CTRL>
DEVINL float dpp_add(float x) {
    int r = __builtin_amdgcn_update_dpp(0, __builtin_bit_cast(int, x),
                                        CTRL, 0xF, 0xF, true);
    return x + __builtin_bit_cast(float, r);
}
DEVINL float red8(float x) {
    x = dpp_add<0xB1>(x);   // quad_perm [1,0,3,2]  : xor1
    x = dpp_add<0x4E>(x);   // quad_perm [2,3,0,1]  : xor2
    x = dpp_add<0x141>(x);  // row_half_mirror      : completes 8-lane sum
    return x;
}

__launch_bounds__(256, 4)
__global__ void k_attn(const unsigned short* __restrict__ qkv,
                       const unsigned int* __restrict__ dkw2,
                       const float* __restrict__ relb,
                       const float* __restrict__ escale,
                       unsigned short* __restrict__ att) {
    __shared__ __align__(16) unsigned int ksh[36 * 128];  // k pairs (c, c+16)
    __shared__ __align__(16) unsigned int vsh[36 * 128];  // v pairs
    __shared__ __align__(16) unsigned int qsh[16 * 128];  // q pairs
    const int t = threadIdx.x;
    const int g = t >> 6;            // pixel slot (0..3)
    const int li = t & 7;            // lane within head-group
    const int head = (t >> 3) & 7;
    const int prA = head * 16 + li;  // dword A: channels (c, c+16)
    const int prB = prA + 8;         // dword B: channels (c+8, c+24)
    const int sA = sg(prA);          // swizzled LDS dword indices
    const int sB = sg(prB);
    const int w0 = blockIdx.x * 4, h0 = blockIdx.y * 4, b = blockIdx.z;

    float rb[9];
    #pragma unroll
    for (int m = 0; m < 9; ++m) rb[m] = relb[head * 9 + m];
    const float es2 = escale[head];          // exp(scale)*log2e

    // stage k/v halo pairs: 36 px x 16 units (unit = data-head*2 + half)
    for (int idx = t; idx < 576; idx += 256) {
        int hp = idx >> 4, u = idx & 15;
        int hh = u >> 1, half = u & 1;
        int cA = hh * 32 + half * 8;
        int hy = h0 - 1 + hp / 6, hx = w0 - 1 + hp % 6;
        i32x4 kA = {0,0,0,0}, kB = {0,0,0,0}, vA = {0,0,0,0}, vB = {0,0,0,0};
        if ((unsigned)hy < 64u && (unsigned)hx < 64u) {
            const unsigned short* base = qkv + ((size_t)((b * 64 + hy) * 64 + hx)) * 768;
            kA = *(const i32x4*)(base + 256 + cA);
            kB = *(const i32x4*)(base + 256 + cA + 16);
            vA = *(const i32x4*)(base + 512 + cA);
            vB = *(const i32x4*)(base + 512 + cA + 16);
        }
        i32x4 kp0, kp1, vp0, vp1;
        #pragma unroll
        for (int e = 0; e < 4; ++e) {
            unsigned klo = __builtin_amdgcn_perm((unsigned)kB[e], (unsigned)kA[e], 0x05040100u);
            unsigned khi = __builtin_amdgcn_perm((unsigned)kB[e], (unsigned)kA[e], 0x07060302u);
            unsigned vlo = __builtin_amdgcn_perm((unsigned)vB[e], (unsigned)vA[e], 0x05040100u);
            unsigned vhi = __builtin_amdgcn_perm((unsigned)vB[e], (unsigned)vA[e], 0x07060302u);
            if (e < 2) {
                kp0[2*e] = (int)klo; kp0[2*e+1] = (int)khi;
                vp0[2*e] = (int)vlo; vp0[2*e+1] = (int)vhi;
            } else {
                kp1[2*(e-2)] = (int)klo; kp1[2*(e-2)+1] = (int)khi;
                vp1[2*(e-2)] = (int)vlo; vp1[2*(e-2)+1] = (int)vhi;
            }
        }
        // sg() is constant across the 8-dword unit (bits 5-6 fixed) ->
        // contiguity and 16B alignment preserved.
        int pi = hp * 128 + sg(hh * 16 + half * 8);
        *(i32x4*)(ksh + pi)     = kp0;
        *(i32x4*)(ksh + pi + 4) = kp1;
        *(i32x4*)(vsh + pi)     = vp0;
        *(i32x4*)(vsh + pi + 4) = vp1;
    }
    // stage q pairs: exactly one unit per thread (16 px x 16 units)
    {
        int px_s = t >> 4, u = t & 15;
        int hh = u >> 1, half = u & 1;
        int cA = hh * 32 + half * 8;
        int iy = h0 + (px_s >> 2), ix = w0 + (px_s & 3);
        const unsigned short* base = qkv + ((size_t)((b * 64 + iy) * 64 + ix)) * 768;
        i32x4 qA = *(const i32x4*)(base + cA);
        i32x4 qB = *(const i32x4*)(base + cA + 16);
        i32x4 qp0, qp1;
        #pragma unroll
        for (int e = 0; e < 4; ++e) {
            unsigned lo = __builtin_amdgcn_perm((unsigned)qB[e], (unsigned)qA[e], 0x05040100u);
            unsigned hi = __builtin_amdgcn_perm((unsigned)qB[e], (unsigned)qA[e], 0x07060302u);
            if (e < 2) { qp0[2*e] = (int)lo; qp0[2*e+1] = (int)hi; }
            else       { qp1[2*(e-2)] = (int)lo; qp1[2*(e-2)+1] = (int)hi; }
        }
        int pi = px_s * 128 + sg(hh * 16 + half * 8);
        *(i32x4*)(qsh + pi)     = qp0;
        *(i32x4*)(qsh + pi + 4) = qp1;
    }
    __syncthreads();

    #pragma unroll 1
    for (int it = 0; it < 4; ++it) {
        const int p = it * 4 + g;
        const int py = p >> 2, px = p & 3;
        const int iy = h0 + py, ix = w0 + px;
        const size_t pix = (size_t)((b * 64 + iy) * 64 + ix);
        const h2 qA = __builtin_bit_cast(h2, qsh[p * 128 + sA]);
        const h2 qB = __builtin_bit_cast(h2, qsh[p * 128 + sB]);

        // conv: ij-outer, all 81 taps (identity weights are exactly 1.0),
        // inputs read from LDS per-ij, weights streamed from L2.
        h2 kaA[9], kaB[9], vaA[9], vaB[9];
        #pragma unroll
        for (int ij = 0; ij < 9; ++ij) {
            const int hp = (py + ij / 3) * 6 + (px + ij % 3);
            const h2 kiA = __builtin_bit_cast(h2, ksh[hp * 128 + sA]);
            const h2 kiB = __builtin_bit_cast(h2, ksh[hp * 128 + sB]);
            const h2 viA = __builtin_bit_cast(h2, vsh[hp * 128 + sA]);
            const h2 viB = __builtin_bit_cast(h2, vsh[hp * 128 + sB]);
            #pragma unroll
            for (int m = 0; m < 9; ++m) {
                const int l = ij * 9 + m;
                h2 wA = __builtin_bit_cast(h2, dkw2[l * 128 + prA]);
                h2 wB = __builtin_bit_cast(h2, dkw2[l * 128 + prB]);
                if (ij == 0) {
                    kaA[m] = kiA * wA;  kaB[m] = kiB * wB;
                    vaA[m] = viA * wA;  vaB[m] = viB * wB;
                } else {
                    kaA[m] = __builtin_elementwise_fma(kiA, wA, kaA[m]);
                    kaB[m] = __builtin_elementwise_fma(kiB, wB, kaB[m]);
                    vaA[m] = __builtin_elementwise_fma(viA, wA, vaA[m]);
                    vaB[m] = __builtin_elementwise_fma(viB, wB, vaB[m]);
                }
            }
        }

        float red[19];
        red[0] = fdot2f(qA, qA, fdot2f(qB, qB, 0.f));
        #pragma unroll
        for (int m = 0; m < 9; ++m) {
            red[1 + m]  = fdot2f(qA, kaA[m], fdot2f(qB, kaB[m], 0.f));
            red[10 + m] = fdot2f(kaA[m], kaA[m], fdot2f(kaB[m], kaB[m], 0.f));
        }
        #pragma unroll
        for (int i = 0; i < 19; ++i) red[i] = red8(red[i]);

        const float rq = __builtin_amdgcn_rsqf(fmaxf(red[0], 1.55e-5f)) * es2;
        const bool yt = (iy == 0), yb = (iy == 63), xl = (ix == 0), xr = (ix == 63);
        const float NEG = -144.2695040888963f;  // -100*log2e
        float e[9], sum = 0.f;
        #pragma unroll
        for (int m = 0; m < 9; ++m) {
            float rk = __builtin_amdgcn_rsqf(fmaxf(red[10 + m], 1.55e-5f));
            int dy = m / 3 - 1, dx = m % 3 - 1;
            bool oob = (dy < 0 && yt) || (dy > 0 && yb) || (dx < 0 && xl) || (dx > 0 && xr);
            float a = red[1 + m] * rq * rk + rb[m] + (oob ? NEG : 0.f);
            e[m] = fexp2(a);            // f32: range-safe without max-subtract
            sum += e[m];
        }
        const float rs = __builtin_amdgcn_rcpf(sum);
        h2 oA = {(_Float16)0.f, (_Float16)0.f};
        h2 oB = {(_Float16)0.f, (_Float16)0.f};
        #pragma unroll
        for (int m = 0; m < 9; ++m) {
            _Float16 ph = (_Float16)(e[m] * rs);   // p in [0,1] -> f16 safe
            h2 pb2 = {ph, ph};
            oA = __builtin_elementwise_fma(vaA[m], pb2, oA);
            oB = __builtin_elementwise_fma(vaB[m], pb2, oB);
        }
        // pair-ordered att row: dword pr holds (att_c, att_c+16)
        *(unsigned int*)(att + pix * 256 + prA * 2) = __builtin_bit_cast(unsigned int, oA);
        *(unsigned int*)(att + pix * 256 + prB * 2) = __builtin_bit_cast(unsigned int, oB);
    }
}

// ------------------------------------------------------------- proj GEMM ----
__launch_bounds__(512, 1)
__global__ void k_proj_gemm(const unsigned short* __restrict__ attin,
                            const unsigned short* __restrict__ pT,
                            const float* __restrict__ pb,
                            float* __restrict__ out) {
    __shared__ __align__(16) unsigned short As[128 * 64];
    __shared__ __align__(16) unsigned short Bs[256 * 64];
    const int t = threadIdx.x;
    const int m0 = blockIdx.x * 128;
    const int wid = t >> 6, lane = t & 63;
    const int wm = wid >> 2, wn = wid & 3;
    const int lr = lane & 15, lk = lane >> 4;
    const int ar = t >> 2, aq = t & 3;
    const int bn = t >> 1, bh = t & 1;
    f32x4 acc[4][4] = {};

    for (int ks = 0; ks < 256; ks += 64) {
        {   // stage A (f16 rows of att, pair-permuted K — matches pT)
            const unsigned short* src = attin + (size_t)(m0 + ar) * 256 + ks + aq * 16;
            s16x8 h0 = *(const s16x8*)(src + 0);
            s16x8 h1 = *(const s16x8*)(src + 8);
            int off = ar * 128 + aq * 32;
            *(s16x8*)((char*)As + swz(off))      = h0;
            *(s16x8*)((char*)As + swz(off + 16)) = h1;
        }
        {   // stage B (f16)
            const unsigned short* src = pT + (size_t)bn * 256 + ks + bh * 32;
            s16x8 b0 = *(const s16x8*)(src + 0);
            s16x8 b1 = *(const s16x8*)(src + 8);
            s16x8 b2 = *(const s16x8*)(src + 16);
            s16x8 b3 = *(const s16x8*)(src + 24);
            int off = bn * 128 + bh * 64;
            *(s16x8*)((char*)Bs + swz(off))      = b0;
            *(s16x8*)((char*)Bs + swz(off + 16)) = b1;
            *(s16x8*)((char*)Bs + swz(off + 32)) = b2;
            *(s16x8*)((char*)Bs + swz(off + 48)) = b3;
        }
        __syncthreads();
        #pragma unroll
        for (int kc = 0; kc < 2; ++kc) {
            s16x8 af[4], bfr[4];
            #pragma unroll
            for (int i = 0; i < 4; ++i) {
                int off = (wm * 64 + i * 16 + lr) * 128 + kc * 64 + lk * 16;
                af[i] = *(const s16x8*)((const char*)As + swz(off));
            }
            #pragma unroll
            for (int i = 0; i < 4; ++i) {
                int off = (wn * 64 + i * 16 + lr) * 128 + kc * 64 + lk * 16;
                bfr[i] = *(const s16x8*)((const char*)Bs + swz(off));
            }
            #pragma unroll
            for (int i = 0; i < 4; ++i)
                #pragma unroll
                for (int j = 0; j < 4; ++j)
                    acc[i][j] = __builtin_amdgcn_mfma_f32_16x16x32_f16(af[i], bfr[j], acc[i][j], 0, 0, 0);
        }
        __syncthreads();
    }
    #pragma unroll
    for (int i = 0; i < 4; ++i) {
        const int mg = m0 + wm * 64 + i * 16 + lk * 4;
        #pragma unroll
        for (int j = 0; j < 4; ++j) {
            const int ng = wn * 64 + j * 16 + lr;
            const float bias = pb[ng];
            #pragma unroll
            for (int e = 0; e < 4; ++e)
                out[(size_t)(mg + e) * 256 + ng] = acc[i][j][e] + bias;
        }
    }
}

// ----------------------------------------------------------------- launch ----
extern "C" void kernel_launch(void* const* d_in, const int* in_sizes, int n_in,
                              void* d_out, int out_size, void* d_ws, size_t ws_size,
                              hipStream_t stream) {
    const float* x  = (const float*)d_in[0];
    const float* wq = (const float*)d_in[1];
    const float* qb = (const float*)d_in[2];
    const float* vb = (const float*)d_in[3];
    const float* dk = (const float*)d_in[4];
    const float* sc = (const float*)d_in[5];
    const float* w1 = (const float*)d_in[6];
    const float* b1 = (const float*)d_in[7];
    const float* w2 = (const float*)d_in[8];
    const float* pw = (const float*)d_in[9];
    const float* pb = (const float*)d_in[10];
    float* out = (float*)d_out;

    char* ws = (char*)d_ws;
    unsigned short* qkv  = (unsigned short*)(ws + 0);          // 50,331,648 B (f16)
    unsigned short* att  = (unsigned short*)(ws + 50331648);   // 16,777,216 B (f16, pair-order)
    unsigned int*   dkw2 = (unsigned int*)(ws + 67108864);     //     41,472 B (81 x 128 words)
    unsigned short* wT   = (unsigned short*)(ws + 67150336);   //    393,216 B (bf16)
    unsigned short* pT   = (unsigned short*)(ws + 67543552);   //    131,072 B (f16, permuted)
    float*          rlb  = (float*)(ws + 67674624);            //        288 B
    float*          esc  = (float*)(ws + 67674912);            //         32 B

    // k_pre: block 0 = setup; blocks 1..474 = transpose (272,512 items / 576)
    hipLaunchKernelGGL(k_pre, dim3(475), dim3(576), 0, stream,
                       sc, w1, b1, w2, dk, wq, pw, rlb, esc, dkw2, wT, pT);
    hipLaunchKernelGGL(k_qkv_gemm, dim3(768), dim3(512), 0, stream, x, wT, qb, vb, qkv);
    hipLaunchKernelGGL(k_attn, dim3(16, 16, 8), dim3(256), 0, stream, qkv, dkw2, rlb, esc, att);
    hipLaunchKernelGGL(k_proj_gemm, dim3(256), dim3(512), 0, stream, att, pT, pb, out);
}